// Round 4
// baseline (377.160 us; speedup 1.0000x reference)
//
#include <hip/hip_runtime.h>
#include <hip/hip_bf16.h>

typedef short bf16x8 __attribute__((ext_vector_type(8)));
typedef float floatx4 __attribute__((ext_vector_type(4)));

union F8 { bf16x8 h; unsigned u[4]; };

// RTNE fp32->bf16 pack of two floats into one dword (lo in low half).
// Branch-free; inputs are finite Gaussians so no NaN path needed.
__device__ __forceinline__ unsigned pk(float lo, float hi) {
  unsigned a = __float_as_uint(lo), b = __float_as_uint(hi);
  a += 0x7fffu + ((a >> 16) & 1u);
  b += 0x7fffu + ((b >> 16) & 1u);
  return (a >> 16) | (b & 0xffff0000u);
}

__device__ __forceinline__ bf16x8 cvt8(const float4& a, const float4& b) {
  F8 u;
  u.u[0] = pk(a.x, a.y); u.u[1] = pk(a.z, a.w);
  u.u[2] = pk(b.x, b.y); u.u[3] = pk(b.z, b.w);
  return u.h;
}

// fp32 in / fp32 out (verified round 3). TWO pixels per wave-iteration:
//   pixel-even: A0 = [dv0 | ze] (k 0-15 dv, 16-31 ze), B = w1 rows k
//   pixel-odd : A1 = [ze | dv1],                       B' = w1 rows (k+16)&31
// Both give dv*w_v + ze*w_e + b1. Within-pixel byte offset 1024t+64m+32(q&1)
// is the same formula for dv and ze, so ALL 64 lanes load dv (q>=2 lanes load
// the odd pixel) -> full-wave coalesced loads. Layout-safe: k-perms cancel
// A<->B; D mapping col=lane&15 (m89-verified) fixes the store lane.
__global__ __launch_bounds__(256, 3) void bev_kernel(
    const float* __restrict__ dv,   // [P][64][16]
    const float* __restrict__ ze,   // [64][16]
    const float* __restrict__ w1,   // [32][64]
    const float* __restrict__ b1,   // [64]
    const float* __restrict__ gam,  // [64]
    const float* __restrict__ bet,  // [64]
    float* __restrict__ out,        // [P][64]
    int P)
{
  const int lane = threadIdx.x & 63;
  const int wid  = blockIdx.x * (blockDim.x >> 6) + (threadIdx.x >> 6);
  const int nw   = gridDim.x * (blockDim.x >> 6);
  const int q = lane >> 4;
  const int m = lane & 15;

  // B fragments: bA[nb] rows q*8+j ; bB[nb] rows (q*8+j+16)&31. col nb*16+m.
  bf16x8 bA[4], bB[4];
  #pragma unroll
  for (int nb = 0; nb < 4; ++nb) {
    const int col = nb * 16 + m;
    F8 ta, tb;
    #pragma unroll
    for (int i = 0; i < 4; ++i) {
      const int rA = q * 8 + 2 * i;
      ta.u[i] = pk(w1[rA * 64 + col], w1[(rA + 1) * 64 + col]);
      const int rB0 = (rA + 16) & 31, rB1 = (rA + 17) & 31;
      tb.u[i] = pk(w1[rB0 * 64 + col], w1[rB1 * 64 + col]);
    }
    bA[nb] = ta.h; bB[nb] = tb.h;
  }
  floatx4 cinit[4];
  #pragma unroll
  for (int nb = 0; nb < 4; ++nb) {
    float b = b1[nb * 16 + m];
    cinit[nb] = (floatx4){b, b, b, b};
  }
  const float gl = gam[lane];
  const float bl = bet[lane];

  // z_embed fragments for ALL lanes (max offset 4080+16 = 4096 = ze size).
  bf16x8 aez[4];
  #pragma unroll
  for (int t = 0; t < 4; ++t) {
    const char* zp = (const char*)ze + 1024 * t + 64 * m + 32 * (q & 1);
    aez[t] = cvt8(*(const float4*)zp, *(const float4*)(zp + 16));
  }

  // dv stream: unit u = pixel pair (2u, 2u+1). q>=2 lanes read the odd pixel.
  const char* p = (const char*)dv + (long)wid * 8192 +
                  (q >= 2 ? 4096 : 0) + 64 * m + 32 * (q & 1);
  const long step = (long)nw * 8192;

  float4 r[8];
  bf16x8 frag[4];
  int u = wid;
  if (2 * u < P) {
    #pragma unroll
    for (int t = 0; t < 4; ++t) {
      r[2 * t]     = *(const float4*)(p + 1024 * t);
      r[2 * t + 1] = *(const float4*)(p + 1024 * t + 16);
    }
    #pragma unroll
    for (int t = 0; t < 4; ++t) frag[t] = cvt8(r[2 * t], r[2 * t + 1]);
  }

  for (; 2 * u < P; u += nw) {
    p += step;
    if (2 * (u + nw) < P) {            // software-pipelined prefetch
      #pragma unroll
      for (int t = 0; t < 4; ++t) {
        r[2 * t]     = *(const float4*)(p + 1024 * t);
        r[2 * t + 1] = *(const float4*)(p + 1024 * t + 16);
      }
    }

    float a0[4] = {0.f, 0.f, 0.f, 0.f};
    float a1[4] = {0.f, 0.f, 0.f, 0.f};
    #pragma unroll
    for (int t = 0; t < 4; ++t) {
      const bf16x8 A0 = (q < 2) ? frag[t] : aez[t];
      const bf16x8 A1 = (q < 2) ? aez[t] : frag[t];
      #pragma unroll
      for (int nb = 0; nb < 4; ++nb) {
        floatx4 d0 = __builtin_amdgcn_mfma_f32_16x16x32_bf16(A0, bA[nb], cinit[nb], 0, 0, 0);
        a0[nb] += (fmaxf(d0[0], 0.f) + fmaxf(d0[1], 0.f)) +
                  (fmaxf(d0[2], 0.f) + fmaxf(d0[3], 0.f));
        floatx4 d1 = __builtin_amdgcn_mfma_f32_16x16x32_bf16(A1, bB[nb], cinit[nb], 0, 0, 0);
        a1[nb] += (fmaxf(d1[0], 0.f) + fmaxf(d1[1], 0.f)) +
                  (fmaxf(d1[2], 0.f) + fmaxf(d1[3], 0.f));
      }
    }
    // complete z-sums across quads (two independent chains -> ILP)
    #pragma unroll
    for (int nb = 0; nb < 4; ++nb) {
      a0[nb] += __shfl_xor(a0[nb], 16, 64);
      a1[nb] += __shfl_xor(a1[nb], 16, 64);
      a0[nb] += __shfl_xor(a0[nb], 32, 64);
      a1[nb] += __shfl_xor(a1[nb], 32, 64);
    }
    // LayerNorm over d=64 for both pixels; lane owns d = nb*16+m.
    float s0 = a0[0] + a0[1] + a0[2] + a0[3];
    float s1 = a1[0] + a1[1] + a1[2] + a1[3];
    float q0 = a0[0]*a0[0] + a0[1]*a0[1] + a0[2]*a0[2] + a0[3]*a0[3];
    float q1 = a1[0]*a1[0] + a1[1]*a1[1] + a1[2]*a1[2] + a1[3]*a1[3];
    #pragma unroll
    for (int off = 1; off <= 8; off <<= 1) {
      s0 += __shfl_xor(s0, off, 64);
      s1 += __shfl_xor(s1, off, 64);
      q0 += __shfl_xor(q0, off, 64);
      q1 += __shfl_xor(q1, off, 64);
    }
    const float mean0 = s0 * 0.015625f, mean1 = s1 * 0.015625f;
    const float rs0 = rsqrtf(q0 * 0.015625f - mean0 * mean0 + 1e-5f);
    const float rs1 = rsqrtf(q1 * 0.015625f - mean1 * mean1 + 1e-5f);
    const float v0 = (q == 0) ? a0[0] : (q == 1) ? a0[1] : (q == 2) ? a0[2] : a0[3];
    const float v1 = (q == 0) ? a1[0] : (q == 1) ? a1[1] : (q == 2) ? a1[2] : a1[3];
    out[(long)u * 128 + lane]      = (v0 - mean0) * rs0 * gl + bl;
    out[(long)u * 128 + 64 + lane] = (v1 - mean1) * rs1 * gl + bl;

    // consume prefetched raw -> fragments for next unit (vmcnt wait lands here)
    #pragma unroll
    for (int t = 0; t < 4; ++t) frag[t] = cvt8(r[2 * t], r[2 * t + 1]);
  }
}

extern "C" void kernel_launch(void* const* d_in, const int* in_sizes, int n_in,
                              void* d_out, int out_size, void* d_ws, size_t ws_size,
                              hipStream_t stream) {
  const float* dv  = (const float*)d_in[0];
  const float* ze  = (const float*)d_in[1];
  const float* w1  = (const float*)d_in[2];
  const float* b1  = (const float*)d_in[3];
  const float* gam = (const float*)d_in[4];
  const float* bet = (const float*)d_in[5];
  float* out = (float*)d_out;

  const int P = in_sizes[0] / (64 * 16);  // H*W pixels (B=1)
  dim3 grid(2048), block(256);            // 8192 waves; P/2=32768 units -> 4/wave
  bev_kernel<<<grid, block, 0, stream>>>(dv, ze, w1, b1, gam, bet, out, P);
}